// Round 5
// baseline (21.488 us; speedup 1.0000x reference)
//
#include <hip/hip_runtime.h>

// Problem constants (from reference): B=16, C=200, K=5, HW=64
constexpr int B_    = 16;
constexpr int C_    = 200;
constexpr int K_    = 5;
constexpr int HW_   = 64;
constexpr int PLANE = HW_ * HW_;             // 4096 elements per (b,c) plane
constexpr int VEC   = 4;                     // float4 per thread
constexpr int PG_PER_IMG = PLANE / VEC;      // 1024 position-groups per image
constexpr int NPG   = B_ * PG_PER_IMG;       // 16384 position-groups total
constexpr int NCHUNK = 10;                   // channel chunks
constexpr int CH    = C_ / NCHUNK;           // 20 channels per chunk
constexpr int THREADS = 256;
constexpr int BLKX  = NPG / THREADS;         // 64 blocks in position dim

typedef float v4f __attribute__((ext_vector_type(4)));  // native vector for nontemporal builtin

// MODE: 0 = first chunk (c0==0), 1 = interior, 2 = last chunk (c0==C-CH)
// NLD: strip length (CH+2 for edge chunks, CH+4 for interior)
template<int MODE, int NLD>
__device__ __forceinline__ void body(int c0,
                                     const float* __restrict__ xb,
                                     const float* __restrict__ W,
                                     const float* __restrict__ bias,
                                     float* __restrict__ ob)
{
    // contiguous strip of NLD channels covering every clamped window of this chunk
    const int cs = (MODE == 0) ? 0 : (MODE == 2 ? (C_ - NLD) : (c0 - 2));

    // issue all strip loads up-front: NLD independent 16B loads in flight
    v4f r[NLD];
    #pragma unroll
    for (int i = 0; i < NLD; ++i)
        r[i] = *(const v4f*)(xb + (size_t)(cs + i) * PLANE);

    #pragma unroll
    for (int i = 0; i < CH; ++i) {
        const int c = c0 + i;
        // window start offset into r[] — compile-time constant after unroll
        int off;
        if (MODE == 0)      off = (i < 2) ? 0 : (i - 2);          // s = max(c-2,0)
        else if (MODE == 2) off = (i < NLD - K_) ? i : (NLD - K_);// s = min(c-2, C-K)
        else                off = i;                              // s = c-2
        // self channel index into r[]: c - cs
        const int si = (MODE == 0) ? i : (i + 2);

        // uniform (blockIdx-derived) addresses -> scalar loads, K$-cached
        const float k0 = W[c * K_ + 0];
        const float k1 = W[c * K_ + 1];
        const float k2 = W[c * K_ + 2];
        const float k3 = W[c * K_ + 3];
        const float k4 = W[c * K_ + 4];
        const float bb = bias[c];

        const v4f self = r[si];
        v4f o = self + bb + r[off] * k0 + r[off+1] * k1 + r[off+2] * k2 + r[off+3] * k3 + r[off+4] * k4;
        // non-temporal: out is write-once, keep it from displacing x in L2/L3
        __builtin_nontemporal_store(o, (v4f*)(ob + (size_t)c * PLANE));
    }
}

__global__ __launch_bounds__(THREADS) void neigh_conv_kernel(
    const float* __restrict__ x,
    const float* __restrict__ W,
    const float* __restrict__ bias,
    float* __restrict__ out)
{
    const int chunk = blockIdx.y;                 // 0..NCHUNK-1, wave-uniform
    const int c0    = chunk * CH;
    const int pg    = blockIdx.x * THREADS + threadIdx.x;  // 0..NPG-1
    const int b     = pg / PG_PER_IMG;
    const int pos   = (pg % PG_PER_IMG) * VEC;

    const float* xb = x   + (size_t)b * C_ * PLANE + pos;
    float*       ob = out + (size_t)b * C_ * PLANE + pos;

    if (chunk == 0)                body<0, CH + 2>(c0, xb, W, bias, ob);
    else if (chunk == NCHUNK - 1)  body<2, CH + 2>(c0, xb, W, bias, ob);
    else                           body<1, CH + 4>(c0, xb, W, bias, ob);
}

extern "C" void kernel_launch(void* const* d_in, const int* in_sizes, int n_in,
                              void* d_out, int out_size, void* d_ws, size_t ws_size,
                              hipStream_t stream) {
    const float* x    = (const float*)d_in[0];
    const float* W    = (const float*)d_in[1];
    const float* bias = (const float*)d_in[2];
    float* out        = (float*)d_out;

    dim3 grid(BLKX, NCHUNK);
    neigh_conv_kernel<<<grid, THREADS, 0, stream>>>(x, W, bias, out);
}

// Round 6
// 21.459 us; speedup vs baseline: 1.0013x; 1.0013x over previous
//
#include <hip/hip_runtime.h>

// Problem constants (from reference): B=16, C=200, K=5, HW=64
constexpr int B_    = 16;
constexpr int C_    = 200;
constexpr int K_    = 5;
constexpr int HW_   = 64;
constexpr int PLANE = HW_ * HW_;             // 4096 elements per (b,c) plane
constexpr int VEC   = 4;                     // float4 per thread
constexpr int PG_PER_IMG = PLANE / VEC;      // 1024 position-groups per image
constexpr int NPG   = B_ * PG_PER_IMG;       // 16384 position-groups total
constexpr int NCHUNK = 10;                   // channel chunks
constexpr int CH    = C_ / NCHUNK;           // 20 channels per chunk
constexpr int THREADS = 128;                 // 128-thread blocks: 1280 blocks = exactly 5/CU
constexpr int BLKX  = NPG / THREADS;         // 128 blocks in position dim

typedef float v4f __attribute__((ext_vector_type(4)));  // native vector for nontemporal builtin

// MODE: 0 = first chunk (c0==0), 1 = interior, 2 = last chunk (c0==C-CH)
// NLD: strip length (CH+2 for edge chunks, CH+4 for interior)
template<int MODE, int NLD>
__device__ __forceinline__ void body(int c0,
                                     const float* __restrict__ xb,
                                     const float* __restrict__ W,
                                     const float* __restrict__ bias,
                                     float* __restrict__ ob)
{
    // contiguous strip of NLD channels covering every clamped window of this chunk
    const int cs = (MODE == 0) ? 0 : (MODE == 2 ? (C_ - NLD) : (c0 - 2));

    // issue all strip loads up-front: NLD independent 16B loads in flight
    v4f r[NLD];
    #pragma unroll
    for (int i = 0; i < NLD; ++i)
        r[i] = *(const v4f*)(xb + (size_t)(cs + i) * PLANE);

    #pragma unroll
    for (int i = 0; i < CH; ++i) {
        const int c = c0 + i;
        // window start offset into r[] — compile-time constant after unroll
        int off;
        if (MODE == 0)      off = (i < 2) ? 0 : (i - 2);          // s = max(c-2,0)
        else if (MODE == 2) off = (i < NLD - K_) ? i : (NLD - K_);// s = min(c-2, C-K)
        else                off = i;                              // s = c-2
        // self channel index into r[]: c - cs
        const int si = (MODE == 0) ? i : (i + 2);

        // uniform (blockIdx-derived) addresses -> scalar loads, K$-cached
        const float k0 = W[c * K_ + 0];
        const float k1 = W[c * K_ + 1];
        const float k2 = W[c * K_ + 2];
        const float k3 = W[c * K_ + 3];
        const float k4 = W[c * K_ + 4];
        const float bb = bias[c];

        const v4f self = r[si];
        v4f o = self + bb + r[off] * k0 + r[off+1] * k1 + r[off+2] * k2 + r[off+3] * k3 + r[off+4] * k4;
        // non-temporal: out is write-once, keep it from displacing x in L2/L3
        __builtin_nontemporal_store(o, (v4f*)(ob + (size_t)c * PLANE));
    }
}

__global__ __launch_bounds__(THREADS) void neigh_conv_kernel(
    const float* __restrict__ x,
    const float* __restrict__ W,
    const float* __restrict__ bias,
    float* __restrict__ out)
{
    const int chunk = blockIdx.y;                 // 0..NCHUNK-1, wave-uniform
    const int c0    = chunk * CH;
    const int pg    = blockIdx.x * THREADS + threadIdx.x;  // 0..NPG-1
    const int b     = pg / PG_PER_IMG;
    const int pos   = (pg % PG_PER_IMG) * VEC;

    const float* xb = x   + (size_t)b * C_ * PLANE + pos;
    float*       ob = out + (size_t)b * C_ * PLANE + pos;

    if (chunk == 0)                body<0, CH + 2>(c0, xb, W, bias, ob);
    else if (chunk == NCHUNK - 1)  body<2, CH + 2>(c0, xb, W, bias, ob);
    else                           body<1, CH + 4>(c0, xb, W, bias, ob);
}

extern "C" void kernel_launch(void* const* d_in, const int* in_sizes, int n_in,
                              void* d_out, int out_size, void* d_ws, size_t ws_size,
                              hipStream_t stream) {
    const float* x    = (const float*)d_in[0];
    const float* W    = (const float*)d_in[1];
    const float* bias = (const float*)d_in[2];
    float* out        = (float*)d_out;

    dim3 grid(BLKX, NCHUNK);
    neigh_conv_kernel<<<grid, THREADS, 0, stream>>>(x, W, bias, out);
}